// Round 9
// baseline (153.655 us; speedup 1.0000x reference)
//
#include <hip/hip_runtime.h>
#include <hip/hip_bf16.h>

using bf16x8  = __attribute__((ext_vector_type(8))) short;
using f32x4   = __attribute__((ext_vector_type(4))) float;
using f32x16  = __attribute__((ext_vector_type(16))) float;
using u32x2_t = __attribute__((ext_vector_type(2))) unsigned int;

#define SEQ      2048
#define DMODEL   1024
#define NHEADS   16
#define HDIM     64
#define MROWS    4096   // BATCH*SEQ

__device__ __forceinline__ unsigned short f2bf(float f) {
  union { float f; unsigned u; } c; c.f = f;
  unsigned r = c.u + 0x7FFFu + ((c.u >> 16) & 1u);
  return (unsigned short)(r >> 16);
}
__device__ __forceinline__ unsigned pk2(float a, float b) {
  return (unsigned)f2bf(a) | ((unsigned)f2bf(b) << 16);
}

__device__ __forceinline__ void gload16(const void* g, void* s) {
  __builtin_amdgcn_global_load_lds(
      (const __attribute__((address_space(1))) void*)g,
      (__attribute__((address_space(3))) void*)s, 16, 0, 0);
}

// lane l<32 keeps a; lane l>=32 gets partner(l-32)'s b  /  second: l<32 gets
// partner(l+32)'s a; l>=32 keeps b.   (v_permlane32_swap_b32)
__device__ __forceinline__ u32x2_t pl32swap(unsigned a, unsigned b) {
#if __has_builtin(__builtin_amdgcn_permlane32_swap)
  return __builtin_amdgcn_permlane32_swap(a, b, false, false);
#else
  unsigned pa = __shfl_xor((int)a, 32);
  unsigned pb = __shfl_xor((int)b, 32);
  int hi = (threadIdx.x & 63) >> 5;
  u32x2_t r;
  r.x = hi ? pb : a;    // slot-low
  r.y = hi ? b  : pa;   // slot-high
  return r;
#endif
}

// ---------------- fp32 -> bf16 conversion, all 5 tensors in one launch -------
__global__ void cvt_all(const float* __restrict__ x,  const float* __restrict__ wq,
                        const float* __restrict__ wk, const float* __restrict__ wv,
                        const float* __restrict__ wo,
                        unsigned short* __restrict__ xb,  unsigned short* __restrict__ wqb,
                        unsigned short* __restrict__ wkb, unsigned short* __restrict__ wvb,
                        unsigned short* __restrict__ wob)
{
  int i = blockIdx.x * blockDim.x + threadIdx.x;   // 0 .. 2097151 float4s
  const float* src; unsigned short* dst; int off;
  if (i < 1048576) { src = x; dst = xb; off = i; }
  else {
    int k = i - 1048576, seg = k >> 18; off = k & 262143;
    if      (seg == 0) { src = wq; dst = wqb; }
    else if (seg == 1) { src = wk; dst = wkb; }
    else if (seg == 2) { src = wv; dst = wvb; }
    else               { src = wo; dst = wob; }
  }
  const float4 v = ((const float4*)src)[off];
  ushort4 o;
  o.x = f2bf(v.x); o.y = f2bf(v.y); o.z = f2bf(v.z); o.w = f2bf(v.w);
  ((ushort4*)dst)[off] = o;
}

// ---------------- fused QKV projection GEMM ---------------------------------
__global__ __launch_bounds__(256, 2)
void gemm_qkv(const unsigned short* __restrict__ Ab,
              const unsigned short* __restrict__ Wqb,
              const unsigned short* __restrict__ Wkb,
              const unsigned short* __restrict__ Wvb,
              const float* __restrict__ bq, const float* __restrict__ bk,
              const float* __restrict__ bv,
              unsigned short* __restrict__ Qo, unsigned short* __restrict__ Ko,
              unsigned short* __restrict__ Vto)
{
  __shared__ unsigned short As[128 * 64];
  __shared__ unsigned short Bs[128 * 64];
  const int t  = threadIdx.x;
  const int w  = t >> 6, l = t & 63;
  const int lr = l & 15, lg = l >> 4;
  const int bm = blockIdx.x / 24;
  const int bn = blockIdx.x % 24;
  const int which = bn >> 3;
  const unsigned short* Bsrc = which == 0 ? Wqb : (which == 1 ? Wkb : Wvb);
  const float* biasp = which == 0 ? bq : (which == 1 ? bk : bv);
  const int bnw = bn & 7;
  const int wm = w >> 1, wn = w & 1;

  const char* Agp = (const char*)Ab + (size_t)bm * 128 * 2048;
  const char* Bgp = (const char*)Bsrc + (size_t)bnw * 128 * 2048;

  f32x4 acc[4][4];
  #pragma unroll
  for (int a = 0; a < 4; ++a)
    #pragma unroll
    for (int b = 0; b < 4; ++b) acc[a][b] = (f32x4){0.f, 0.f, 0.f, 0.f};

  for (int kt = 0; kt < 16; ++kt) {
    const int kbyte = kt * 128;
    #pragma unroll
    for (int i = 0; i < 4; ++i) {
      int idx  = i * 256 + t;
      int row  = idx >> 3;
      int colb = (idx & 7) << 4;
      gload16(Agp + (size_t)row * 2048 + kbyte + colb, (char*)As + idx * 16);
      gload16(Bgp + (size_t)row * 2048 + kbyte + colb, (char*)Bs + idx * 16);
    }
    __syncthreads();
    #pragma unroll
    for (int kk = 0; kk < 2; ++kk) {
      bf16x8 af[4], bfr[4];
      #pragma unroll
      for (int x = 0; x < 4; ++x) {
        af[x]  = *(const bf16x8*)&As[(wm * 64 + x * 16 + lr) * 64 + kk * 32 + lg * 8];
        bfr[x] = *(const bf16x8*)&Bs[(wn * 64 + x * 16 + lr) * 64 + kk * 32 + lg * 8];
      }
      #pragma unroll
      for (int xa = 0; xa < 4; ++xa)
        #pragma unroll
        for (int xb = 0; xb < 4; ++xb)
          acc[xa][xb] = __builtin_amdgcn_mfma_f32_16x16x32_bf16(af[xa], bfr[xb], acc[xa][xb], 0, 0, 0);
    }
    __syncthreads();
  }

  #pragma unroll
  for (int xb = 0; xb < 4; ++xb) {
    int colg = bnw * 128 + wn * 64 + xb * 16 + lr;
    int h  = colg >> 6, dh = colg & 63;
    float biasv = biasp[colg];
    #pragma unroll
    for (int xa = 0; xa < 4; ++xa) {
      int row0 = bm * 128 + wm * 64 + xa * 16 + lg * 4;
      #pragma unroll
      for (int i = 0; i < 4; ++i) {
        int m = row0 + i;
        int b = m >> 11, s = m & 2047;
        unsigned short u = f2bf(acc[xa][xb][i] + biasv);
        if (which == 0)
          Qo[(((size_t)(b * NHEADS + h)) * SEQ + s) * HDIM + dh] = u;
        else if (which == 1)
          Ko[(((size_t)(b * NHEADS + h)) * SEQ + s) * HDIM + dh] = u;
        else
          Vto[(((size_t)(b * NHEADS + h)) * HDIM + dh) * SEQ + s] = u;
      }
    }
  }
}

// ---------------- causal flash attention helpers -----------------------------
// Stage a 128-key trip: K tile [128 key][64 dh] (16 KB) + V tile [64 dh][128 key]
// (16 KB). 256 threads, 8 x 16B each; XOR-swizzled via pre-swizzled source.
__device__ __forceinline__ void stage_kv128(const char* Kg, const char* Vg,
                                            char* Kl, char* Vl, int nb, int t)
{
  #pragma unroll
  for (int i = 0; i < 4; ++i) {
    int idx = i * 256 + t;
    int row = idx >> 3, colb = (idx & 7) << 4;
    int scol = colb ^ ((row & 7) << 4);
    gload16(Kg + (size_t)(nb + row) * 128 + scol, Kl + idx * 16);
    int vr = idx >> 4, vcb = (idx & 15) << 4;
    int vsc = vcb ^ ((vr & 7) << 4);
    gload16(Vg + (size_t)vr * 4096 + (size_t)nb * 2 + vsc, Vl + idx * 16);
  }
}

// One 64-key subtile, 32x32x16 swapped-QK^T, in-register softmax (T12 port).
// C of mfma(K,Q) = S^T: lane(hi,lo) reg r holds S^T[key=kbase+kt*32+crow][q=q0w+lo],
// crow = (r&3)+8*(r>>2)+4*hi.  P->bf16 packs + permlane32_swap rebuild PV's
// A-frags in registers (no P-LDS). O,L accumulate in matching C layout.
template<int SUB>
__device__ __forceinline__ void attn_sub64(const char* Kl, const char* Vl,
                                           const bf16x8 (&qf)[4], const bf16x8 ones,
                                           f32x16 (&o0)[1], f32x16 (&o1)[1], f32x16 &accL,
                                           int q0w, int kbase, int lo, int hi)
{
  if (kbase > q0w + 31) return;                 // wave-uniform skip
  const bool needMask = (kbase + 63 > q0w);
  #pragma unroll
  for (int kt = 0; kt < 2; ++kt) {
    // ---- K A-frags: lane holds K[SUB*64+kt*32+lo][dh = s*16 + hi*8 + e]
    bf16x8 kf[4];
    #pragma unroll
    for (int s = 0; s < 4; ++s)
      kf[s] = *(const bf16x8*)(Kl + (size_t)(SUB * 64 + kt * 32 + lo) * 128 +
                               ((s * 32 + hi * 16) ^ ((lo & 7) << 4)));
    // ---- S^T = K @ Q^T
    f32x16 st = {0.f};
    #pragma unroll
    for (int s = 0; s < 4; ++s)
      st = __builtin_amdgcn_mfma_f32_32x32x16_bf16(kf[s], qf[s], st, 0, 0, 0);
    // ---- mask + exp (p = exp2(s * 0.125*log2e)); masked -> exp(-inf) = 0
    float p[16];
    #pragma unroll
    for (int r = 0; r < 16; ++r) {
      int crow = (r & 3) + 8 * (r >> 2) + 4 * hi;
      float sv = st[r];
      if (needMask && (kbase + kt * 32 + crow > q0w + lo)) sv = -3.0e38f;
      p[r] = exp2f(sv * 0.180336881f);
    }
    // ---- pack to bf16 pairs (consecutive keys)
    unsigned wq[8];
    #pragma unroll
    for (int j = 0; j < 8; ++j) wq[j] = pk2(p[2 * j], p[2 * j + 1]);
    // ---- permlane32_swap -> PV A-frags for the kt tile's two 16-key steps
    u32x2_t r02 = pl32swap(wq[0], wq[2]);
    u32x2_t r13 = pl32swap(wq[1], wq[3]);
    u32x2_t r46 = pl32swap(wq[4], wq[6]);
    u32x2_t r57 = pl32swap(wq[5], wq[7]);
    union { unsigned u[4]; bf16x8 v; } pa0, pa1;
    pa0.u[0] = r02.x; pa0.u[1] = r13.x; pa0.u[2] = r02.y; pa0.u[3] = r13.y;
    pa1.u[0] = r46.x; pa1.u[1] = r57.x; pa1.u[2] = r46.y; pa1.u[3] = r57.y;
    // ---- PV + L for steps st'=0,1 (keys SUB*64 + kt*32 + st'*16 + ..)
    #pragma unroll
    for (int sp = 0; sp < 2; ++sp) {
      const bf16x8 pa = sp ? pa1.v : pa0.v;
      const int kbyte = SUB * 128 + kt * 64 + sp * 32 + hi * 16;
      bf16x8 vf0 = *(const bf16x8*)(Vl + (size_t)(lo) * 256 +
                                    (kbyte ^ ((lo & 7) << 4)));
      bf16x8 vf1 = *(const bf16x8*)(Vl + (size_t)(32 + lo) * 256 +
                                    (kbyte ^ ((lo & 7) << 4)));
      o0[0] = __builtin_amdgcn_mfma_f32_32x32x16_bf16(pa, vf0, o0[0], 0, 0, 0);
      o1[0] = __builtin_amdgcn_mfma_f32_32x32x16_bf16(pa, vf1, o1[0], 0, 0, 0);
      accL  = __builtin_amdgcn_mfma_f32_32x32x16_bf16(pa, ones, accL, 0, 0, 0);
    }
  }
}

// ---------------- causal flash attention -------------------------------------
// grid = 512 = 16 qt-slots * 32 bh; 256 thr = 4 waves * 32 q-rows (32x32 MFMA).
// qt order [0,2,..,14,1,3,..,15]: co-resident blocks b,b+256 have near-equal
// trip counts (R8 lesson: concurrent makespan = max -> pair EQUAL lengths).
// LDS exactly 64 KB (K/V 128-key dbuf) -> 2 blocks/CU; no P-LDS (in-reg T12).
__global__ __launch_bounds__(256)
void attn_fwd(const unsigned short* __restrict__ Q,
              const unsigned short* __restrict__ K,
              const unsigned short* __restrict__ Vt,
              unsigned short* __restrict__ O)
{
  const int t = threadIdx.x;
  const int w = t >> 6, l = t & 63;
  const int lo = l & 31, hi = l >> 5;
  const int bh  = blockIdx.x & 31;
  const int idx = blockIdx.x >> 5;               // 0..15
  const int qt  = (idx < 8) ? 2 * idx : 2 * (idx - 8) + 1;
  const int b = bh >> 4, h = bh & 15;
  const int q0w = qt * 128 + w * 32;

  const unsigned short* Qp = Q + (size_t)bh * SEQ * HDIM;
  const char* Kg = (const char*)(K  + (size_t)bh * SEQ * HDIM);
  const char* Vg = (const char*)(Vt + (size_t)bh * HDIM * SEQ);

  __shared__ unsigned short Klds[2][128 * 64];   // 2 x 16 KB [key][dh] swizzled
  __shared__ unsigned short Vlds[2][64 * 128];   // 2 x 16 KB [dh][key] swizzled

  // Q B-frags: lane holds Q[q0w+lo][dh = s*16 + hi*8 + e]
  bf16x8 qf[4];
  #pragma unroll
  for (int s = 0; s < 4; ++s)
    qf[s] = *(const bf16x8*)(Qp + (size_t)(q0w + lo) * HDIM + s * 16 + hi * 8);

  bf16x8 ones;
  #pragma unroll
  for (int e = 0; e < 8; ++e) ones[e] = (short)0x3F80;   // bf16 1.0

  f32x16 o0[1], o1[1], accL;
  o0[0] = (f32x16){0.f}; o1[0] = (f32x16){0.f}; accL = (f32x16){0.f};

  const int trips = qt + 1;   // 128-key tiles

  stage_kv128(Kg, Vg, (char*)Klds[0], (char*)Vlds[0], 0, t);
  __syncthreads();
  int cur = 0;
  for (int kb = 0; kb < trips; ++kb) {
    if (kb + 1 < trips)
      stage_kv128(Kg, Vg, (char*)Klds[cur ^ 1], (char*)Vlds[cur ^ 1], (kb + 1) * 128, t);
    const int kbase = kb * 128;
    attn_sub64<0>((const char*)Klds[cur], (const char*)Vlds[cur], qf, ones,
                  o0, o1, accL, q0w, kbase, lo, hi);
    attn_sub64<1>((const char*)Klds[cur], (const char*)Vlds[cur], qf, ones,
                  o0, o1, accL, q0w, kbase + 64, lo, hi);
    __syncthreads();
    cur ^= 1;
  }

  // epilogue: O[q][dh]/L[q]; lane(hi,lo) reg r -> q = q0w+crow, dh = dt*32+lo
  #pragma unroll
  for (int r = 0; r < 16; ++r) {
    int crow = (r & 3) + 8 * (r >> 2) + 4 * hi;
    int srow = q0w + crow;
    float linv = 1.0f / accL[r];
    size_t base = ((size_t)(b * SEQ + srow)) * DMODEL + h * HDIM;
    O[base + lo]      = f2bf(o0[0][r] * linv);
    O[base + 32 + lo] = f2bf(o1[0][r] * linv);
  }
}

// ---------------- output projection GEMM (fp32 out + bias) ------------------
__global__ __launch_bounds__(256, 2)
void gemm_out(const unsigned short* __restrict__ Ab, const unsigned short* __restrict__ Bb,
              const float* __restrict__ bias, float* __restrict__ C)
{
  __shared__ unsigned short As[128 * 64];
  __shared__ unsigned short Bs[128 * 64];
  const int t  = threadIdx.x;
  const int w  = t >> 6, l = t & 63;
  const int lr = l & 15, lg = l >> 4;
  const int bm = blockIdx.x >> 3;
  const int bn = blockIdx.x & 7;
  const int wm = w >> 1, wn = w & 1;

  const char* Agp = (const char*)Ab + (size_t)bm * 128 * 2048;
  const char* Bgp = (const char*)Bb + (size_t)bn * 128 * 2048;

  f32x4 acc[4][4];
  #pragma unroll
  for (int a = 0; a < 4; ++a)
    #pragma unroll
    for (int b = 0; b < 4; ++b) acc[a][b] = (f32x4){0.f, 0.f, 0.f, 0.f};

  for (int kt = 0; kt < 16; ++kt) {
    const int kbyte = kt * 128;
    #pragma unroll
    for (int i = 0; i < 4; ++i) {
      int idx  = i * 256 + t;
      int row  = idx >> 3;
      int colb = (idx & 7) << 4;
      gload16(Agp + (size_t)row * 2048 + kbyte + colb, (char*)As + idx * 16);
      gload16(Bgp + (size_t)row * 2048 + kbyte + colb, (char*)Bs + idx * 16);
    }
    __syncthreads();
    #pragma unroll
    for (int kk = 0; kk < 2; ++kk) {
      bf16x8 af[4], bfr[4];
      #pragma unroll
      for (int x = 0; x < 4; ++x) {
        af[x]  = *(const bf16x8*)&As[(wm * 64 + x * 16 + lr) * 64 + kk * 32 + lg * 8];
        bfr[x] = *(const bf16x8*)&Bs[(wn * 64 + x * 16 + lr) * 64 + kk * 32 + lg * 8];
      }
      #pragma unroll
      for (int xa = 0; xa < 4; ++xa)
        #pragma unroll
        for (int xb = 0; xb < 4; ++xb)
          acc[xa][xb] = __builtin_amdgcn_mfma_f32_16x16x32_bf16(af[xa], bfr[xb], acc[xa][xb], 0, 0, 0);
    }
    __syncthreads();
  }
  #pragma unroll
  for (int xb = 0; xb < 4; ++xb) {
    int col = bn * 128 + wn * 64 + xb * 16 + lr;
    float bvv = bias[col];
    #pragma unroll
    for (int xa = 0; xa < 4; ++xa) {
      int row0 = bm * 128 + wm * 64 + xa * 16 + lg * 4;
      #pragma unroll
      for (int i = 0; i < 4; ++i)
        C[(size_t)(row0 + i) * DMODEL + col] = acc[xa][xb][i] + bvv;
    }
  }
}

// ---------------- launcher ---------------------------------------------------
extern "C" void kernel_launch(void* const* d_in, const int* in_sizes, int n_in,
                              void* d_out, int out_size, void* d_ws, size_t ws_size,
                              hipStream_t stream)
{
  const float* x  = (const float*)d_in[0];
  // d_in[1] is the causal mask — constant tril, applied analytically in attn_fwd.
  const float* Wq = (const float*)d_in[2];
  const float* bq = (const float*)d_in[3];
  const float* Wk = (const float*)d_in[4];
  const float* bk = (const float*)d_in[5];
  const float* Wv = (const float*)d_in[6];
  const float* bv = (const float*)d_in[7];
  const float* Wo = (const float*)d_in[8];
  const float* bo = (const float*)d_in[9];

  char* ws = (char*)d_ws;
  const size_t MB = 1024 * 1024;
  unsigned short* xb   = (unsigned short*)(ws + 0);        // 8 MB  [4096][1024]
  unsigned short* Wqb  = (unsigned short*)(ws + 8  * MB);  // 2 MB
  unsigned short* Wkb  = (unsigned short*)(ws + 10 * MB);  // 2 MB
  unsigned short* Wvb  = (unsigned short*)(ws + 12 * MB);  // 2 MB
  unsigned short* Wob  = (unsigned short*)(ws + 14 * MB);  // 2 MB
  unsigned short* Qb   = (unsigned short*)(ws + 16 * MB);  // 8 MB  [(bh)*S+s][dh]
  unsigned short* Kb   = (unsigned short*)(ws + 24 * MB);  // 8 MB  [(bh)*S+s][dh]
  unsigned short* Vtb  = (unsigned short*)(ws + 32 * MB);  // 8 MB  [(bh)*64+dh][s]
  unsigned short* Attn = (unsigned short*)(ws + 40 * MB);  // 8 MB  [b*S+s][dmodel]

  cvt_all<<<8192, 256, 0, stream>>>(x, Wq, Wk, Wv, Wo, xb, Wqb, Wkb, Wvb, Wob);
  gemm_qkv<<<768, 256, 0, stream>>>(xb, Wqb, Wkb, Wvb, bq, bk, bv, Qb, Kb, Vtb);
  attn_fwd<<<512, 256, 0, stream>>>(Qb, Kb, Vtb, Attn);
  gemm_out<<<256, 256, 0, stream>>>(Attn, Wob, bo, (float*)d_out);
}

// Round 10
// 128.919 us; speedup vs baseline: 1.1919x; 1.1919x over previous
//
#include <hip/hip_runtime.h>
#include <hip/hip_bf16.h>

using bf16x8 = __attribute__((ext_vector_type(8))) short;
using f32x4  = __attribute__((ext_vector_type(4))) float;

#define SEQ      2048
#define DMODEL   1024
#define NHEADS   16
#define HDIM     64
#define MROWS    4096   // BATCH*SEQ

__device__ __forceinline__ unsigned short f2bf(float f) {
  union { float f; unsigned u; } c; c.f = f;
  unsigned r = c.u + 0x7FFFu + ((c.u >> 16) & 1u);
  return (unsigned short)(r >> 16);
}

__device__ __forceinline__ void gload16(const void* g, void* s) {
  __builtin_amdgcn_global_load_lds(
      (const __attribute__((address_space(1))) void*)g,
      (__attribute__((address_space(3))) void*)s, 16, 0, 0);
}

// ---------------- fp32 -> bf16 conversion, all 5 tensors in one launch -------
__global__ void cvt_all(const float* __restrict__ x,  const float* __restrict__ wq,
                        const float* __restrict__ wk, const float* __restrict__ wv,
                        const float* __restrict__ wo,
                        unsigned short* __restrict__ xb,  unsigned short* __restrict__ wqb,
                        unsigned short* __restrict__ wkb, unsigned short* __restrict__ wvb,
                        unsigned short* __restrict__ wob)
{
  int i = blockIdx.x * blockDim.x + threadIdx.x;   // 0 .. 2097151 float4s
  const float* src; unsigned short* dst; int off;
  if (i < 1048576) { src = x; dst = xb; off = i; }
  else {
    int k = i - 1048576, seg = k >> 18; off = k & 262143;
    if      (seg == 0) { src = wq; dst = wqb; }
    else if (seg == 1) { src = wk; dst = wkb; }
    else if (seg == 2) { src = wv; dst = wvb; }
    else               { src = wo; dst = wob; }
  }
  const float4 v = ((const float4*)src)[off];
  ushort4 o;
  o.x = f2bf(v.x); o.y = f2bf(v.y); o.z = f2bf(v.z); o.w = f2bf(v.w);
  ((ushort4*)dst)[off] = o;
}

// ---------------- fused QKV projection GEMM ---------------------------------
__global__ __launch_bounds__(256, 2)
void gemm_qkv(const unsigned short* __restrict__ Ab,
              const unsigned short* __restrict__ Wqb,
              const unsigned short* __restrict__ Wkb,
              const unsigned short* __restrict__ Wvb,
              const float* __restrict__ bq, const float* __restrict__ bk,
              const float* __restrict__ bv,
              unsigned short* __restrict__ Qo, unsigned short* __restrict__ Ko,
              unsigned short* __restrict__ Vto)
{
  __shared__ unsigned short As[128 * 64];
  __shared__ unsigned short Bs[128 * 64];
  const int t  = threadIdx.x;
  const int w  = t >> 6, l = t & 63;
  const int lr = l & 15, lg = l >> 4;
  const int bm = blockIdx.x / 24;
  const int bn = blockIdx.x % 24;
  const int which = bn >> 3;
  const unsigned short* Bsrc = which == 0 ? Wqb : (which == 1 ? Wkb : Wvb);
  const float* biasp = which == 0 ? bq : (which == 1 ? bk : bv);
  const int bnw = bn & 7;
  const int wm = w >> 1, wn = w & 1;

  const char* Agp = (const char*)Ab + (size_t)bm * 128 * 2048;
  const char* Bgp = (const char*)Bsrc + (size_t)bnw * 128 * 2048;

  f32x4 acc[4][4];
  #pragma unroll
  for (int a = 0; a < 4; ++a)
    #pragma unroll
    for (int b = 0; b < 4; ++b) acc[a][b] = (f32x4){0.f, 0.f, 0.f, 0.f};

  for (int kt = 0; kt < 16; ++kt) {
    const int kbyte = kt * 128;
    #pragma unroll
    for (int i = 0; i < 4; ++i) {
      int idx  = i * 256 + t;
      int row  = idx >> 3;
      int colb = (idx & 7) << 4;
      gload16(Agp + (size_t)row * 2048 + kbyte + colb, (char*)As + idx * 16);
      gload16(Bgp + (size_t)row * 2048 + kbyte + colb, (char*)Bs + idx * 16);
    }
    __syncthreads();
    #pragma unroll
    for (int kk = 0; kk < 2; ++kk) {
      bf16x8 af[4], bfr[4];
      #pragma unroll
      for (int x = 0; x < 4; ++x) {
        af[x]  = *(const bf16x8*)&As[(wm * 64 + x * 16 + lr) * 64 + kk * 32 + lg * 8];
        bfr[x] = *(const bf16x8*)&Bs[(wn * 64 + x * 16 + lr) * 64 + kk * 32 + lg * 8];
      }
      #pragma unroll
      for (int xa = 0; xa < 4; ++xa)
        #pragma unroll
        for (int xb = 0; xb < 4; ++xb)
          acc[xa][xb] = __builtin_amdgcn_mfma_f32_16x16x32_bf16(af[xa], bfr[xb], acc[xa][xb], 0, 0, 0);
    }
    __syncthreads();
  }

  #pragma unroll
  for (int xb = 0; xb < 4; ++xb) {
    int colg = bnw * 128 + wn * 64 + xb * 16 + lr;
    int h  = colg >> 6, dh = colg & 63;
    float biasv = biasp[colg];
    #pragma unroll
    for (int xa = 0; xa < 4; ++xa) {
      int row0 = bm * 128 + wm * 64 + xa * 16 + lg * 4;
      #pragma unroll
      for (int i = 0; i < 4; ++i) {
        int m = row0 + i;
        int b = m >> 11, s = m & 2047;
        unsigned short u = f2bf(acc[xa][xb][i] + biasv);
        if (which == 0)
          Qo[(((size_t)(b * NHEADS + h)) * SEQ + s) * HDIM + dh] = u;
        else if (which == 1)
          Ko[(((size_t)(b * NHEADS + h)) * SEQ + s) * HDIM + dh] = u;
        else
          Vto[(((size_t)(b * NHEADS + h)) * HDIM + dh) * SEQ + s] = u;
      }
    }
  }
}

// ---------------- causal flash attention helpers -----------------------------
// 256-thread staging of a 64-key tile: K 64x64 bf16 (8 KB) + V^T 64x64 (8 KB),
// 2 x 16B chunks per thread each, XOR-swizzled via pre-swizzled global source.
__device__ __forceinline__ void stage_kv64(const char* Kg, const char* Vg,
                                           char* Kl, char* Vl, int nb, int t)
{
  #pragma unroll
  for (int i = 0; i < 2; ++i) {
    int idx = i * 256 + t;
    int row = idx >> 3, colb = (idx & 7) << 4;
    int scol = colb ^ ((row & 7) << 4);
    gload16(Kg + (size_t)(nb + row) * 128 + scol, Kl + idx * 16);
    gload16(Vg + (size_t)row * 4096 + (size_t)nb * 2 + scol, Vl + idx * 16);
  }
}

// One 64-key subtile for a 16-row wave: S = QK^T, mask, P = exp2(S*c) via LDS,
// O += P@V, L += P@1.  All register arrays statically indexed (rule #20).
__device__ __forceinline__ void attn_sub16(const char* Kl, const char* Vl, char* Pw,
                                           const bf16x8 (&qf)[2], const bf16x8 ones,
                                           f32x4 (&o)[4], f32x4 &accL,
                                           int q0w, int kbase, bool diag, int lr, int lg)
{
  bf16x8 kf[4][2];
  #pragma unroll
  for (int n = 0; n < 4; ++n)
    #pragma unroll
    for (int kk = 0; kk < 2; ++kk)
      kf[n][kk] = *(const bf16x8*)(Kl + (size_t)(n * 16 + lr) * 128 +
                                   ((kk * 64 + lg * 16) ^ ((lr & 7) << 4)));
  f32x4 s[4];
  __builtin_amdgcn_s_setprio(1);
  #pragma unroll
  for (int n = 0; n < 4; ++n) {
    f32x4 acc = (f32x4){0.f, 0.f, 0.f, 0.f};
    #pragma unroll
    for (int kk = 0; kk < 2; ++kk)
      acc = __builtin_amdgcn_mfma_f32_16x16x32_bf16(qf[kk], kf[n][kk], acc, 0, 0, 0);
    s[n] = acc;
  }
  __builtin_amdgcn_s_setprio(0);
  if (diag) {                    // diagonal-overlapping subtile: causal mask
    #pragma unroll
    for (int n = 0; n < 4; ++n) {
      int key = kbase + n * 16 + lr;
      #pragma unroll
      for (int i = 0; i < 4; ++i) {
        int query = q0w + lg * 4 + i;
        if (key > query) s[n][i] = -3.0e38f;
      }
    }
  }
  #pragma unroll
  for (int n = 0; n < 4; ++n)
    #pragma unroll
    for (int i = 0; i < 4; ++i) {
      float p = exp2f(s[n][i] * 0.180336881f);   // 0.125 * log2(e)
      union { float fl; unsigned u; } cv; cv.fl = p;
      int prow = lg * 4 + i;
      int pcb  = ((n * 16 + lr) * 2) ^ ((prow & 7) << 4);
      *(unsigned short*)(Pw + prow * 128 + pcb) =
          (unsigned short)((cv.u + 0x8000u) >> 16);
    }
  __builtin_amdgcn_s_setprio(1);
  #pragma unroll
  for (int kk = 0; kk < 2; ++kk) {
    bf16x8 af = *(const bf16x8*)(Pw + lr * 128 + ((kk * 64 + lg * 16) ^ ((lr & 7) << 4)));
    accL = __builtin_amdgcn_mfma_f32_16x16x32_bf16(af, ones, accL, 0, 0, 0);
    #pragma unroll
    for (int n = 0; n < 4; ++n) {
      bf16x8 vf = *(const bf16x8*)(Vl + (size_t)(n * 16 + lr) * 128 +
                    ((kk * 64 + lg * 16) ^ ((lr & 7) << 4)));
      o[n] = __builtin_amdgcn_mfma_f32_16x16x32_bf16(af, vf, o[n], 0, 0, 0);
    }
  }
  __builtin_amdgcn_s_setprio(0);
}

// ---------------- causal flash attention -------------------------------------
// grid = 1024 = 32 qt-slots * 32 bh; 256 thr = 4 waves * 16 q-rows.
// Block owns a 64-row q-tile (qt*64); wave w rows q0w = qt*64 + w*16 -> every
// wave runs every trip (no skips, lockstep-friendly), diagonal mask on last.
// LDS exactly 40 KB (K 16 + V 16 dbuf + swizzled P 8) -> 4 blocks/CU
// = 16 waves/CU = 4 waves/SIMD.  Co-resident blocks are independent
// (different bh/qt -> desynced phases fill each other's barrier/vmcnt drains;
// R5-R9 evidence: elapsed 8.4K cy/trip vs 3K issue -> 60% stall at 2 w/SIMD).
// slot->qt = (s&1) ? 31-s/2 : s/2 interleaves long/short for refill smoothing.
__global__ __launch_bounds__(256, 4)
void attn_fwd(const unsigned short* __restrict__ Q,
              const unsigned short* __restrict__ K,
              const unsigned short* __restrict__ Vt,
              unsigned short* __restrict__ O)
{
  const int t = threadIdx.x;
  const int w = t >> 6, l = t & 63;
  const int lr = l & 15, lg = l >> 4;
  const int bh   = blockIdx.x & 31;
  const int slot = blockIdx.x >> 5;            // 0..31
  const int qt   = (slot & 1) ? (31 - (slot >> 1)) : (slot >> 1);
  const int b = bh >> 4, h = bh & 15;
  const int q0w = qt * 64 + w * 16;

  const unsigned short* Qp = Q + (size_t)bh * SEQ * HDIM;
  const char* Kg = (const char*)(K  + (size_t)bh * SEQ * HDIM);
  const char* Vg = (const char*)(Vt + (size_t)bh * HDIM * SEQ);

  __shared__ unsigned short Klds[2][64 * 64];    // 16 KB [key][dh] swizzled
  __shared__ unsigned short Vlds[2][64 * 64];    // 16 KB [dh][key] swizzled
  __shared__ unsigned short Plds[4][16][64];     //  8 KB per-wave P, swizzled
  char* Pw = (char*)Plds[w];

  bf16x8 qf[2];
  #pragma unroll
  for (int kk = 0; kk < 2; ++kk)
    qf[kk] = *(const bf16x8*)(Qp + (size_t)(q0w + lr) * HDIM + kk * 32 + lg * 8);

  bf16x8 ones;
  #pragma unroll
  for (int e = 0; e < 8; ++e) ones[e] = (short)0x3F80;   // bf16 1.0

  f32x4 o[4];
  f32x4 accL = (f32x4){0.f, 0.f, 0.f, 0.f};
  #pragma unroll
  for (int n = 0; n < 4; ++n) o[n] = (f32x4){0.f, 0.f, 0.f, 0.f};

  const int trips = qt + 1;   // 64-key subtiles; all 4 waves run all trips

  stage_kv64(Kg, Vg, (char*)Klds[0], (char*)Vlds[0], 0, t);
  __syncthreads();
  int cur = 0;
  for (int kb = 0; kb < trips; ++kb) {
    if (kb + 1 < trips)
      stage_kv64(Kg, Vg, (char*)Klds[cur ^ 1], (char*)Vlds[cur ^ 1], (kb + 1) * 64, t);
    attn_sub16((const char*)Klds[cur], (const char*)Vlds[cur], Pw, qf, ones,
               o, accL, q0w, kb * 64, kb == trips - 1, lr, lg);
    __syncthreads();
    cur ^= 1;
  }

  // epilogue: normalize by L, write attn[(b*S+s)][h*64+dh]
  #pragma unroll
  for (int n = 0; n < 4; ++n) {
    int col = h * HDIM + n * 16 + lr;
    #pragma unroll
    for (int i = 0; i < 4; ++i) {
      int srow = q0w + lg * 4 + i;
      O[((size_t)(b * SEQ + srow)) * DMODEL + col] = f2bf(o[n][i] / accL[i]);
    }
  }
}

// ---------------- output projection GEMM (fp32 out + bias) ------------------
__global__ __launch_bounds__(256, 2)
void gemm_out(const unsigned short* __restrict__ Ab, const unsigned short* __restrict__ Bb,
              const float* __restrict__ bias, float* __restrict__ C)
{
  __shared__ unsigned short As[128 * 64];
  __shared__ unsigned short Bs[128 * 64];
  const int t  = threadIdx.x;
  const int w  = t >> 6, l = t & 63;
  const int lr = l & 15, lg = l >> 4;
  const int bm = blockIdx.x >> 3;
  const int bn = blockIdx.x & 7;
  const int wm = w >> 1, wn = w & 1;

  const char* Agp = (const char*)Ab + (size_t)bm * 128 * 2048;
  const char* Bgp = (const char*)Bb + (size_t)bn * 128 * 2048;

  f32x4 acc[4][4];
  #pragma unroll
  for (int a = 0; a < 4; ++a)
    #pragma unroll
    for (int b = 0; b < 4; ++b) acc[a][b] = (f32x4){0.f, 0.f, 0.f, 0.f};

  for (int kt = 0; kt < 16; ++kt) {
    const int kbyte = kt * 128;
    #pragma unroll
    for (int i = 0; i < 4; ++i) {
      int idx  = i * 256 + t;
      int row  = idx >> 3;
      int colb = (idx & 7) << 4;
      gload16(Agp + (size_t)row * 2048 + kbyte + colb, (char*)As + idx * 16);
      gload16(Bgp + (size_t)row * 2048 + kbyte + colb, (char*)Bs + idx * 16);
    }
    __syncthreads();
    #pragma unroll
    for (int kk = 0; kk < 2; ++kk) {
      bf16x8 af[4], bfr[4];
      #pragma unroll
      for (int x = 0; x < 4; ++x) {
        af[x]  = *(const bf16x8*)&As[(wm * 64 + x * 16 + lr) * 64 + kk * 32 + lg * 8];
        bfr[x] = *(const bf16x8*)&Bs[(wn * 64 + x * 16 + lr) * 64 + kk * 32 + lg * 8];
      }
      #pragma unroll
      for (int xa = 0; xa < 4; ++xa)
        #pragma unroll
        for (int xb = 0; xb < 4; ++xb)
          acc[xa][xb] = __builtin_amdgcn_mfma_f32_16x16x32_bf16(af[xa], bfr[xb], acc[xa][xb], 0, 0, 0);
    }
    __syncthreads();
  }
  #pragma unroll
  for (int xb = 0; xb < 4; ++xb) {
    int col = bn * 128 + wn * 64 + xb * 16 + lr;
    float bvv = bias[col];
    #pragma unroll
    for (int xa = 0; xa < 4; ++xa) {
      int row0 = bm * 128 + wm * 64 + xa * 16 + lg * 4;
      #pragma unroll
      for (int i = 0; i < 4; ++i)
        C[(size_t)(row0 + i) * DMODEL + col] = acc[xa][xb][i] + bvv;
    }
  }
}

// ---------------- launcher ---------------------------------------------------
extern "C" void kernel_launch(void* const* d_in, const int* in_sizes, int n_in,
                              void* d_out, int out_size, void* d_ws, size_t ws_size,
                              hipStream_t stream)
{
  const float* x  = (const float*)d_in[0];
  // d_in[1] is the causal mask — constant tril, applied analytically in attn_fwd.
  const float* Wq = (const float*)d_in[2];
  const float* bq = (const float*)d_in[3];
  const float* Wk = (const float*)d_in[4];
  const float* bk = (const float*)d_in[5];
  const float* Wv = (const float*)d_in[6];
  const float* bv = (const float*)d_in[7];
  const float* Wo = (const float*)d_in[8];
  const float* bo = (const float*)d_in[9];

  char* ws = (char*)d_ws;
  const size_t MB = 1024 * 1024;
  unsigned short* xb   = (unsigned short*)(ws + 0);        // 8 MB  [4096][1024]
  unsigned short* Wqb  = (unsigned short*)(ws + 8  * MB);  // 2 MB
  unsigned short* Wkb  = (unsigned short*)(ws + 10 * MB);  // 2 MB
  unsigned short* Wvb  = (unsigned short*)(ws + 12 * MB);  // 2 MB
  unsigned short* Wob  = (unsigned short*)(ws + 14 * MB);  // 2 MB
  unsigned short* Qb   = (unsigned short*)(ws + 16 * MB);  // 8 MB  [(bh)*S+s][dh]
  unsigned short* Kb   = (unsigned short*)(ws + 24 * MB);  // 8 MB  [(bh)*S+s][dh]
  unsigned short* Vtb  = (unsigned short*)(ws + 32 * MB);  // 8 MB  [(bh)*64+dh][s]
  unsigned short* Attn = (unsigned short*)(ws + 40 * MB);  // 8 MB  [b*S+s][dmodel]

  cvt_all<<<8192, 256, 0, stream>>>(x, Wq, Wk, Wv, Wo, xb, Wqb, Wkb, Wvb, Wob);
  gemm_qkv<<<768, 256, 0, stream>>>(xb, Wqb, Wkb, Wvb, bq, bk, bv, Qb, Kb, Vtb);
  attn_fwd<<<1024, 256, 0, stream>>>(Qb, Kb, Vtb, Attn);
  gemm_out<<<256, 256, 0, stream>>>(Attn, Wob, bo, (float*)d_out);
}

// Round 11
// 122.125 us; speedup vs baseline: 1.2582x; 1.0556x over previous
//
#include <hip/hip_runtime.h>
#include <hip/hip_bf16.h>

using bf16x8 = __attribute__((ext_vector_type(8))) short;
using f32x4  = __attribute__((ext_vector_type(4))) float;

#define SEQ      2048
#define DMODEL   1024
#define NHEADS   16
#define HDIM     64
#define MROWS    4096   // BATCH*SEQ

__device__ __forceinline__ unsigned short f2bf(float f) {
  union { float f; unsigned u; } c; c.f = f;
  unsigned r = c.u + 0x7FFFu + ((c.u >> 16) & 1u);
  return (unsigned short)(r >> 16);
}

__device__ __forceinline__ void gload16(const void* g, void* s) {
  __builtin_amdgcn_global_load_lds(
      (const __attribute__((address_space(1))) void*)g,
      (__attribute__((address_space(3))) void*)s, 16, 0, 0);
}

// ---------------- fp32 -> bf16 conversion, all 5 tensors in one launch -------
__global__ void cvt_all(const float* __restrict__ x,  const float* __restrict__ wq,
                        const float* __restrict__ wk, const float* __restrict__ wv,
                        const float* __restrict__ wo,
                        unsigned short* __restrict__ xb,  unsigned short* __restrict__ wqb,
                        unsigned short* __restrict__ wkb, unsigned short* __restrict__ wvb,
                        unsigned short* __restrict__ wob)
{
  int i = blockIdx.x * blockDim.x + threadIdx.x;   // 0 .. 2097151 float4s
  const float* src; unsigned short* dst; int off;
  if (i < 1048576) { src = x; dst = xb; off = i; }
  else {
    int k = i - 1048576, seg = k >> 18; off = k & 262143;
    if      (seg == 0) { src = wq; dst = wqb; }
    else if (seg == 1) { src = wk; dst = wkb; }
    else if (seg == 2) { src = wv; dst = wvb; }
    else               { src = wo; dst = wob; }
  }
  const float4 v = ((const float4*)src)[off];
  ushort4 o;
  o.x = f2bf(v.x); o.y = f2bf(v.y); o.z = f2bf(v.z); o.w = f2bf(v.w);
  ((ushort4*)dst)[off] = o;
}

// ---------------- fused QKV projection GEMM ---------------------------------
__global__ __launch_bounds__(256, 2)
void gemm_qkv(const unsigned short* __restrict__ Ab,
              const unsigned short* __restrict__ Wqb,
              const unsigned short* __restrict__ Wkb,
              const unsigned short* __restrict__ Wvb,
              const float* __restrict__ bq, const float* __restrict__ bk,
              const float* __restrict__ bv,
              unsigned short* __restrict__ Qo, unsigned short* __restrict__ Ko,
              unsigned short* __restrict__ Vto)
{
  __shared__ unsigned short As[128 * 64];
  __shared__ unsigned short Bs[128 * 64];
  const int t  = threadIdx.x;
  const int w  = t >> 6, l = t & 63;
  const int lr = l & 15, lg = l >> 4;
  const int bm = blockIdx.x / 24;
  const int bn = blockIdx.x % 24;
  const int which = bn >> 3;
  const unsigned short* Bsrc = which == 0 ? Wqb : (which == 1 ? Wkb : Wvb);
  const float* biasp = which == 0 ? bq : (which == 1 ? bk : bv);
  const int bnw = bn & 7;
  const int wm = w >> 1, wn = w & 1;

  const char* Agp = (const char*)Ab + (size_t)bm * 128 * 2048;
  const char* Bgp = (const char*)Bsrc + (size_t)bnw * 128 * 2048;

  f32x4 acc[4][4];
  #pragma unroll
  for (int a = 0; a < 4; ++a)
    #pragma unroll
    for (int b = 0; b < 4; ++b) acc[a][b] = (f32x4){0.f, 0.f, 0.f, 0.f};

  for (int kt = 0; kt < 16; ++kt) {
    const int kbyte = kt * 128;
    #pragma unroll
    for (int i = 0; i < 4; ++i) {
      int idx  = i * 256 + t;
      int row  = idx >> 3;
      int colb = (idx & 7) << 4;
      gload16(Agp + (size_t)row * 2048 + kbyte + colb, (char*)As + idx * 16);
      gload16(Bgp + (size_t)row * 2048 + kbyte + colb, (char*)Bs + idx * 16);
    }
    __syncthreads();
    #pragma unroll
    for (int kk = 0; kk < 2; ++kk) {
      bf16x8 af[4], bfr[4];
      #pragma unroll
      for (int x = 0; x < 4; ++x) {
        af[x]  = *(const bf16x8*)&As[(wm * 64 + x * 16 + lr) * 64 + kk * 32 + lg * 8];
        bfr[x] = *(const bf16x8*)&Bs[(wn * 64 + x * 16 + lr) * 64 + kk * 32 + lg * 8];
      }
      #pragma unroll
      for (int xa = 0; xa < 4; ++xa)
        #pragma unroll
        for (int xb = 0; xb < 4; ++xb)
          acc[xa][xb] = __builtin_amdgcn_mfma_f32_16x16x32_bf16(af[xa], bfr[xb], acc[xa][xb], 0, 0, 0);
    }
    __syncthreads();
  }

  #pragma unroll
  for (int xb = 0; xb < 4; ++xb) {
    int colg = bnw * 128 + wn * 64 + xb * 16 + lr;
    int h  = colg >> 6, dh = colg & 63;
    float biasv = biasp[colg];
    #pragma unroll
    for (int xa = 0; xa < 4; ++xa) {
      int row0 = bm * 128 + wm * 64 + xa * 16 + lg * 4;
      #pragma unroll
      for (int i = 0; i < 4; ++i) {
        int m = row0 + i;
        int b = m >> 11, s = m & 2047;
        unsigned short u = f2bf(acc[xa][xb][i] + biasv);
        if (which == 0)
          Qo[(((size_t)(b * NHEADS + h)) * SEQ + s) * HDIM + dh] = u;
        else if (which == 1)
          Ko[(((size_t)(b * NHEADS + h)) * SEQ + s) * HDIM + dh] = u;
        else
          Vto[(((size_t)(b * NHEADS + h)) * HDIM + dh) * SEQ + s] = u;
      }
    }
  }
}

// ---------------- causal flash attention helpers -----------------------------
// 256-thread staging of a 64-key tile: K 64x64 bf16 (8 KB) + V^T 64x64 (8 KB),
// 2 x 16B chunks per thread each, XOR-swizzled via pre-swizzled global source.
__device__ __forceinline__ void stage_kv64(const char* Kg, const char* Vg,
                                           char* Kl, char* Vl, int nb, int t)
{
  #pragma unroll
  for (int i = 0; i < 2; ++i) {
    int idx = i * 256 + t;
    int row = idx >> 3, colb = (idx & 7) << 4;
    int scol = colb ^ ((row & 7) << 4);
    gload16(Kg + (size_t)(nb + row) * 128 + scol, Kl + idx * 16);
    gload16(Vg + (size_t)row * 4096 + (size_t)nb * 2 + scol, Vl + idx * 16);
  }
}

// One 64-key subtile for a 16-row wave: S = QK^T, mask, P = exp2(S*c) via LDS,
// O += P@V, L += P@1.  All register arrays statically indexed (rule #20).
__device__ __forceinline__ void attn_sub16(const char* Kl, const char* Vl, char* Pw,
                                           const bf16x8 (&qf)[2], const bf16x8 ones,
                                           f32x4 (&o)[4], f32x4 &accL,
                                           int q0w, int kbase, bool diag, int lr, int lg)
{
  bf16x8 kf[4][2];
  #pragma unroll
  for (int n = 0; n < 4; ++n)
    #pragma unroll
    for (int kk = 0; kk < 2; ++kk)
      kf[n][kk] = *(const bf16x8*)(Kl + (size_t)(n * 16 + lr) * 128 +
                                   ((kk * 64 + lg * 16) ^ ((lr & 7) << 4)));
  f32x4 s[4];
  __builtin_amdgcn_s_setprio(1);
  #pragma unroll
  for (int n = 0; n < 4; ++n) {
    f32x4 acc = (f32x4){0.f, 0.f, 0.f, 0.f};
    #pragma unroll
    for (int kk = 0; kk < 2; ++kk)
      acc = __builtin_amdgcn_mfma_f32_16x16x32_bf16(qf[kk], kf[n][kk], acc, 0, 0, 0);
    s[n] = acc;
  }
  __builtin_amdgcn_s_setprio(0);
  if (diag) {                    // diagonal-overlapping subtile: causal mask
    #pragma unroll
    for (int n = 0; n < 4; ++n) {
      int key = kbase + n * 16 + lr;
      #pragma unroll
      for (int i = 0; i < 4; ++i) {
        int query = q0w + lg * 4 + i;
        if (key > query) s[n][i] = -3.0e38f;
      }
    }
  }
  #pragma unroll
  for (int n = 0; n < 4; ++n)
    #pragma unroll
    for (int i = 0; i < 4; ++i) {
      float p = exp2f(s[n][i] * 0.180336881f);   // 0.125 * log2(e)
      union { float fl; unsigned u; } cv; cv.fl = p;
      int prow = lg * 4 + i;
      int pcb  = ((n * 16 + lr) * 2) ^ ((prow & 7) << 4);
      *(unsigned short*)(Pw + prow * 128 + pcb) =
          (unsigned short)((cv.u + 0x8000u) >> 16);
    }
  __builtin_amdgcn_s_setprio(1);
  #pragma unroll
  for (int kk = 0; kk < 2; ++kk) {
    bf16x8 af = *(const bf16x8*)(Pw + lr * 128 + ((kk * 64 + lg * 16) ^ ((lr & 7) << 4)));
    accL = __builtin_amdgcn_mfma_f32_16x16x32_bf16(af, ones, accL, 0, 0, 0);
    #pragma unroll
    for (int n = 0; n < 4; ++n) {
      bf16x8 vf = *(const bf16x8*)(Vl + (size_t)(n * 16 + lr) * 128 +
                    ((kk * 64 + lg * 16) ^ ((lr & 7) << 4)));
      o[n] = __builtin_amdgcn_mfma_f32_16x16x32_bf16(af, vf, o[n], 0, 0, 0);
    }
  }
  __builtin_amdgcn_s_setprio(0);
}

// ---------------- causal flash attention -------------------------------------
// grid = 1024 = 32 qt-slots * 32 bh; 256 thr = 4 waves * 16 q-rows.
// Block owns a 64-row q-tile; wave w rows q0w = qt*64 + w*16 (all waves run
// all trips). LDS 40 KB -> 4 blocks/CU. Co-resident blocks are i, i+256,
// i+512, i+768 -> slots {s, s+8, s+16, s+24} with the SAME bh (K/V L2/L1
// prefix sharing). slot->qt permutation chosen so each co-resident group's
// trip counts sum to exactly 66:  {s, 23-(s+8), s+16, 55-(s+24)} ->
// {s, 15-s, 16+s, 31-s}, sum of (qt+1) = 66.  (R10 lesson: the previous
// interleave gave groups of 26 vs 104 trips -> 4x per-CU makespan imbalance,
// occupancy 23%.)
__global__ __launch_bounds__(256, 4)
void attn_fwd(const unsigned short* __restrict__ Q,
              const unsigned short* __restrict__ K,
              const unsigned short* __restrict__ Vt,
              unsigned short* __restrict__ O)
{
  const int t = threadIdx.x;
  const int w = t >> 6, l = t & 63;
  const int lr = l & 15, lg = l >> 4;
  const int bh   = blockIdx.x & 31;
  const int slot = blockIdx.x >> 5;            // 0..31
  const int qt   = (slot < 8)  ? slot
                 : (slot < 16) ? (23 - slot)
                 : (slot < 24) ? slot
                 :               (55 - slot);
  const int b = bh >> 4, h = bh & 15;
  const int q0w = qt * 64 + w * 16;

  const unsigned short* Qp = Q + (size_t)bh * SEQ * HDIM;
  const char* Kg = (const char*)(K  + (size_t)bh * SEQ * HDIM);
  const char* Vg = (const char*)(Vt + (size_t)bh * HDIM * SEQ);

  __shared__ unsigned short Klds[2][64 * 64];    // 16 KB [key][dh] swizzled
  __shared__ unsigned short Vlds[2][64 * 64];    // 16 KB [dh][key] swizzled
  __shared__ unsigned short Plds[4][16][64];     //  8 KB per-wave P, swizzled
  char* Pw = (char*)Plds[w];

  bf16x8 qf[2];
  #pragma unroll
  for (int kk = 0; kk < 2; ++kk)
    qf[kk] = *(const bf16x8*)(Qp + (size_t)(q0w + lr) * HDIM + kk * 32 + lg * 8);

  bf16x8 ones;
  #pragma unroll
  for (int e = 0; e < 8; ++e) ones[e] = (short)0x3F80;   // bf16 1.0

  f32x4 o[4];
  f32x4 accL = (f32x4){0.f, 0.f, 0.f, 0.f};
  #pragma unroll
  for (int n = 0; n < 4; ++n) o[n] = (f32x4){0.f, 0.f, 0.f, 0.f};

  const int trips = qt + 1;   // 64-key subtiles; all 4 waves run all trips

  stage_kv64(Kg, Vg, (char*)Klds[0], (char*)Vlds[0], 0, t);
  __syncthreads();
  int cur = 0;
  for (int kb = 0; kb < trips; ++kb) {
    if (kb + 1 < trips)
      stage_kv64(Kg, Vg, (char*)Klds[cur ^ 1], (char*)Vlds[cur ^ 1], (kb + 1) * 64, t);
    attn_sub16((const char*)Klds[cur], (const char*)Vlds[cur], Pw, qf, ones,
               o, accL, q0w, kb * 64, kb == trips - 1, lr, lg);
    __syncthreads();
    cur ^= 1;
  }

  // epilogue: normalize by L, write attn[(b*S+s)][h*64+dh]
  #pragma unroll
  for (int n = 0; n < 4; ++n) {
    int col = h * HDIM + n * 16 + lr;
    #pragma unroll
    for (int i = 0; i < 4; ++i) {
      int srow = q0w + lg * 4 + i;
      O[((size_t)(b * SEQ + srow)) * DMODEL + col] = f2bf(o[n][i] / accL[i]);
    }
  }
}

// ---------------- output projection GEMM (fp32 out + bias) ------------------
__global__ __launch_bounds__(256, 2)
void gemm_out(const unsigned short* __restrict__ Ab, const unsigned short* __restrict__ Bb,
              const float* __restrict__ bias, float* __restrict__ C)
{
  __shared__ unsigned short As[128 * 64];
  __shared__ unsigned short Bs[128 * 64];
  const int t  = threadIdx.x;
  const int w  = t >> 6, l = t & 63;
  const int lr = l & 15, lg = l >> 4;
  const int bm = blockIdx.x >> 3;
  const int bn = blockIdx.x & 7;
  const int wm = w >> 1, wn = w & 1;

  const char* Agp = (const char*)Ab + (size_t)bm * 128 * 2048;
  const char* Bgp = (const char*)Bb + (size_t)bn * 128 * 2048;

  f32x4 acc[4][4];
  #pragma unroll
  for (int a = 0; a < 4; ++a)
    #pragma unroll
    for (int b = 0; b < 4; ++b) acc[a][b] = (f32x4){0.f, 0.f, 0.f, 0.f};

  for (int kt = 0; kt < 16; ++kt) {
    const int kbyte = kt * 128;
    #pragma unroll
    for (int i = 0; i < 4; ++i) {
      int idx  = i * 256 + t;
      int row  = idx >> 3;
      int colb = (idx & 7) << 4;
      gload16(Agp + (size_t)row * 2048 + kbyte + colb, (char*)As + idx * 16);
      gload16(Bgp + (size_t)row * 2048 + kbyte + colb, (char*)Bs + idx * 16);
    }
    __syncthreads();
    #pragma unroll
    for (int kk = 0; kk < 2; ++kk) {
      bf16x8 af[4], bfr[4];
      #pragma unroll
      for (int x = 0; x < 4; ++x) {
        af[x]  = *(const bf16x8*)&As[(wm * 64 + x * 16 + lr) * 64 + kk * 32 + lg * 8];
        bfr[x] = *(const bf16x8*)&Bs[(wn * 64 + x * 16 + lr) * 64 + kk * 32 + lg * 8];
      }
      #pragma unroll
      for (int xa = 0; xa < 4; ++xa)
        #pragma unroll
        for (int xb = 0; xb < 4; ++xb)
          acc[xa][xb] = __builtin_amdgcn_mfma_f32_16x16x32_bf16(af[xa], bfr[xb], acc[xa][xb], 0, 0, 0);
    }
    __syncthreads();
  }
  #pragma unroll
  for (int xb = 0; xb < 4; ++xb) {
    int col = bn * 128 + wn * 64 + xb * 16 + lr;
    float bvv = bias[col];
    #pragma unroll
    for (int xa = 0; xa < 4; ++xa) {
      int row0 = bm * 128 + wm * 64 + xa * 16 + lg * 4;
      #pragma unroll
      for (int i = 0; i < 4; ++i)
        C[(size_t)(row0 + i) * DMODEL + col] = acc[xa][xb][i] + bvv;
    }
  }
}

// ---------------- launcher ---------------------------------------------------
extern "C" void kernel_launch(void* const* d_in, const int* in_sizes, int n_in,
                              void* d_out, int out_size, void* d_ws, size_t ws_size,
                              hipStream_t stream)
{
  const float* x  = (const float*)d_in[0];
  // d_in[1] is the causal mask — constant tril, applied analytically in attn_fwd.
  const float* Wq = (const float*)d_in[2];
  const float* bq = (const float*)d_in[3];
  const float* Wk = (const float*)d_in[4];
  const float* bk = (const float*)d_in[5];
  const float* Wv = (const float*)d_in[6];
  const float* bv = (const float*)d_in[7];
  const float* Wo = (const float*)d_in[8];
  const float* bo = (const float*)d_in[9];

  char* ws = (char*)d_ws;
  const size_t MB = 1024 * 1024;
  unsigned short* xb   = (unsigned short*)(ws + 0);        // 8 MB  [4096][1024]
  unsigned short* Wqb  = (unsigned short*)(ws + 8  * MB);  // 2 MB
  unsigned short* Wkb  = (unsigned short*)(ws + 10 * MB);  // 2 MB
  unsigned short* Wvb  = (unsigned short*)(ws + 12 * MB);  // 2 MB
  unsigned short* Wob  = (unsigned short*)(ws + 14 * MB);  // 2 MB
  unsigned short* Qb   = (unsigned short*)(ws + 16 * MB);  // 8 MB  [(bh)*S+s][dh]
  unsigned short* Kb   = (unsigned short*)(ws + 24 * MB);  // 8 MB  [(bh)*S+s][dh]
  unsigned short* Vtb  = (unsigned short*)(ws + 32 * MB);  // 8 MB  [(bh)*64+dh][s]
  unsigned short* Attn = (unsigned short*)(ws + 40 * MB);  // 8 MB  [b*S+s][dmodel]

  cvt_all<<<8192, 256, 0, stream>>>(x, Wq, Wk, Wv, Wo, xb, Wqb, Wkb, Wvb, Wob);
  gemm_qkv<<<768, 256, 0, stream>>>(xb, Wqb, Wkb, Wvb, bq, bk, bv, Qb, Kb, Vtb);
  attn_fwd<<<1024, 256, 0, stream>>>(Qb, Kb, Vtb, Attn);
  gemm_out<<<256, 256, 0, stream>>>(Attn, Wob, bo, (float*)d_out);
}